// Round 18
// baseline (177.922 us; speedup 1.0000x reference)
//
#include <hip/hip_runtime.h>

#define NROWS  65536
#define DIM    256
#define KCB    1024
#define DELTA  0.012f
#define DELTA2 2.0e-4f
#define NRMAX  65536

typedef __attribute__((ext_vector_type(8))) _Float16 v8h;
typedef __attribute__((ext_vector_type(4))) float v4f;
typedef __attribute__((ext_vector_type(4))) int   v4i;

__device__ __forceinline__ unsigned short h16(float x) {
  _Float16 h = (_Float16)x;                 // v_cvt_f16_f32, RNE
  return __builtin_bit_cast(unsigned short, h);
}
__device__ __forceinline__ unsigned pk2h(float a, float b) {
  return (unsigned)h16(a) | ((unsigned)h16(b) << 16);
}
__device__ __forceinline__ v4i pk8h(float4 a, float4 b) {
  v4i r; r.x = (int)pk2h(a.x,a.y); r.y = (int)pk2h(a.z,a.w);
  r.z = (int)pk2h(b.x,b.y); r.w = (int)pk2h(b.z,b.w);
  return r;
}
__device__ __forceinline__ float f16f(float x) { return (float)(_Float16)x; }
__device__ __forceinline__ void gld16(const void* g, void* l) {
  __builtin_amdgcn_global_load_lds(
      (const __attribute__((address_space(1))) unsigned int*)g,
      (__attribute__((address_space(3))) unsigned int*)l, 16, 0, 0);
}

// ---------------- prep: codebook norms + fp16 hi/lo swizzled-LDS-image codebook ----------------
// layout: [chunk g : 32][code c : 128][k : 64] fp16, k swizzled: pos=(k8*8)^((c&7)<<3)
__global__ __launch_bounds__(256) void prep_kernel(const float* __restrict__ cb,
                                                   float* __restrict__ cnorm,
                                                   unsigned short* __restrict__ cbh,
                                                   unsigned short* __restrict__ cbl,
                                                   int* __restrict__ cnt,
                                                   int* __restrict__ cnt2) {
  int g = blockIdx.x * 256 + threadIdx.x;   // 4096 threads: code k = g>>2, quarter q = g&3
  if (g == 0) { *cnt = 0; *cnt2 = 0; }
  int k = g >> 2, q = g & 3;
  int nt = k >> 7, c = k & 127;
  const float4* row = reinterpret_cast<const float4*>(cb + (size_t)k * DIM) + q * 16;
  size_t off = (size_t)((nt * 4 + q) * 128 + c) * 64;
  unsigned short* dh = cbh + off;
  unsigned short* dl = cbl + off;
  int xr = (c & 7) << 3;
  double s = 0.0;
#pragma unroll
  for (int i = 0; i < 8; ++i) {
    float4 a = row[2 * i], b = row[2 * i + 1];
    s += (double)a.x * a.x + (double)a.y * a.y + (double)a.z * a.z + (double)a.w * a.w;
    s += (double)b.x * b.x + (double)b.y * b.y + (double)b.z * b.z + (double)b.w * b.w;
    *(v4i*)(dh + ((i * 8) ^ xr)) = pk8h(a, b);
    float4 ar, br;
    ar.x = a.x - f16f(a.x); ar.y = a.y - f16f(a.y);
    ar.z = a.z - f16f(a.z); ar.w = a.w - f16f(a.w);
    br.x = b.x - f16f(b.x); br.y = b.y - f16f(b.y);
    br.z = b.z - f16f(b.z); br.w = b.w - f16f(b.w);
    *(v4i*)(dl + ((i * 8) ^ xr)) = pk8h(ar, br);
  }
  s += __shfl_xor(s, 1);
  s += __shfl_xor(s, 2);
  if (q == 0) cnorm[k] = (float)s;
}

// ---------------- stage 1: fp16 MFMA screening, A-frags global->reg, 32KB LDS ----------------
// No Z LDS stage: A fragment (row, k-slice) is 32B contiguous in z per lane ->
// direct float4 loads + v_cvt (bit-identical to the pk8h->LDS->read path).
// LDS = C double-buffer only (2x16KB) -> 3-4 blocks/CU (was 2). Loop = r10-proven
// 16KB-chunk structure; MFMA k-order ascending, scores bit-identical to r15.
__global__ __launch_bounds__(256, 2) void vq_mfma(
    const float* __restrict__ z, const unsigned short* __restrict__ cbh,
    const float* __restrict__ cnw, int* __restrict__ idx_arr,
    int* __restrict__ list, int* __restrict__ cnt) {
  __shared__ __align__(16) short Cs[2][8192];   // 32KB

  const int t = threadIdx.x;
  const int l = t & 63;
  const int w = t >> 6;
  const int l15 = l & 15, lhi = l >> 4;
  const int wm = w * 32;
  const int r0 = blockIdx.x * 128;

  // A fragments: 2 row-frags x 8 k-slices, direct from z (fp32 -> fp16 RNE)
  v8h A[2][8];
#pragma unroll
  for (int mf = 0; mf < 2; ++mf) {
    const float* zr = z + (size_t)(r0 + wm + mf * 16 + l15) * DIM;
#pragma unroll
    for (int ks8 = 0; ks8 < 8; ++ks8) {
      const float* p = zr + ks8 * 32 + lhi * 8;
      float4 a = *(const float4*)p, b = *(const float4*)(p + 4);
      v8h hv;
      hv[0] = (_Float16)a.x; hv[1] = (_Float16)a.y;
      hv[2] = (_Float16)a.z; hv[3] = (_Float16)a.w;
      hv[4] = (_Float16)b.x; hv[5] = (_Float16)b.y;
      hv[6] = (_Float16)b.z; hv[7] = (_Float16)b.w;
      A[mf][ks8] = hv;
    }
  }

  auto stageC = [&](int g) {   // 16KB chunk g -> buffer g&1 (4 gld16/thread)
    const char* gb = (const char*)cbh + (size_t)g * 16384 + w * 4096 + l * 16;
    char* lb = (char*)Cs[g & 1] + w * 4096;
#pragma unroll
    for (int j = 0; j < 4; ++j) gld16(gb + j * 1024, lb + j * 1024);
  };

  int bcode[8], boff[8], bxr[8];
#pragma unroll
  for (int nf = 0; nf < 8; ++nf) {
    bcode[nf] = nf * 16 + l15;
    boff[nf] = bcode[nf] * 64;
    bxr[nf] = (bcode[nf] & 7) << 3;
  }

  float m1[8], m2[8]; int i1[8];
#pragma unroll
  for (int sl = 0; sl < 8; ++sl) { m1[sl] = 3.0e38f; m2[sl] = 3.0e38f; i1[sl] = 0; }

  v4f acc[2][8];

  stageC(0);
  __syncthreads();

  for (int g = 0; g < 32; ++g) {
    if (g < 31) stageC(g + 1);       // prefetch next chunk ∥ compute
    const int kc = g & 3;
    if (kc == 0) {
#pragma unroll
      for (int mf = 0; mf < 2; ++mf)
#pragma unroll
        for (int nf = 0; nf < 8; ++nf) acc[mf][nf] = (v4f){0.f, 0.f, 0.f, 0.f};
    }
    const short* cur = Cs[g & 1];
#pragma unroll
    for (int ks = 0; ks < 2; ++ks) {   // global k-slice kc*2+ks (ascending, same as r15)
      int ko = ks * 32 + lhi * 8;
      v8h b[8];
#pragma unroll
      for (int nf = 0; nf < 8; ++nf)
        b[nf] = *(const v8h*)(cur + boff[nf] + (ko ^ bxr[nf]));
#pragma unroll
      for (int mf = 0; mf < 2; ++mf)
#pragma unroll
        for (int nf = 0; nf < 8; ++nf)
          acc[mf][nf] = __builtin_amdgcn_mfma_f32_16x16x32_f16(A[mf][kc * 2 + ks], b[nf], acc[mf][nf], 0, 0, 0);
    }
    if (kc == 3) {
      int nt = g >> 2;
#pragma unroll
      for (int mf = 0; mf < 2; ++mf)
#pragma unroll
        for (int nf = 0; nf < 8; ++nf) {
          int code = nt * 128 + bcode[nf];
          float cn = cnw[code];
#pragma unroll
          for (int r = 0; r < 4; ++r) {
            float s = fmaf(-2.f, acc[mf][nf][r], cn);
            int sl = mf * 4 + r;
            m2[sl] = fminf(m2[sl], fmaxf(m1[sl], s));
            bool lt = s < m1[sl];
            i1[sl] = lt ? code : i1[sl];
            m1[sl] = lt ? s : m1[sl];
          }
        }
    }
    __syncthreads();   // drains glds; next buffer ready
  }

  // cross-lane argmin over the 16 code-lanes (verbatim r15)
#pragma unroll
  for (int off = 1; off < 16; off <<= 1) {
#pragma unroll
    for (int sl = 0; sl < 8; ++sl) {
      float o1 = __shfl_xor(m1[sl], off);
      int   oi = __shfl_xor(i1[sl], off);
      float o2 = __shfl_xor(m2[sl], off);
      bool bb = (o1 < m1[sl]) || (o1 == m1[sl] && oi < i1[sl]);
      float hi = fmaxf(m1[sl], o1);
      m2[sl] = fminf(hi, fminf(m2[sl], o2));
      m1[sl] = bb ? o1 : m1[sl];
      i1[sl] = bb ? oi : i1[sl];
    }
  }

  if (l15 == 0) {
#pragma unroll
    for (int sl = 0; sl < 8; ++sl) {
      int row = wm + (sl >> 2) * 16 + lhi * 4 + (sl & 3);
      idx_arr[r0 + row] = i1[sl];
      if (m2[sl] - m1[sl] < DELTA) {
        int p = atomicAdd(cnt, 1);
        list[p] = r0 + row;
      }
    }
  }
}

// ---------------- stage 2: split-fp16 refine, code-quarter split (r15 verbatim, (256,1)) ----------------
__global__ __launch_bounds__(256, 1) void vq_refine(
    const float* __restrict__ z,
    const unsigned short* __restrict__ cbh, const unsigned short* __restrict__ cbl,
    const float* __restrict__ cnw, const int* __restrict__ list,
    const int* __restrict__ cnt,
    float* __restrict__ pm1, float* __restrict__ pm2, int* __restrict__ pi1) {
  __shared__ __align__(16) short Ch[2][8192];  // 2 x 16KB
  __shared__ __align__(16) short Cl[2][8192];  // 2 x 16KB
  __shared__ int rows_s[64];

  const int t = threadIdx.x;
  const int l = t & 63, w = t >> 6;
  const int l15 = l & 15, lhi = l >> 4;
  const int n = *cnt;
  const int ngroups = (n + 63) >> 6;
  const int cq = blockIdx.x & 3;

  auto stage2 = [&](int g, int buf) {
    size_t go = (size_t)g * 16384 + w * 4096 + l * 16;
    char* lh = (char*)Ch[buf] + w * 4096;
    char* ll = (char*)Cl[buf] + w * 4096;
#pragma unroll
    for (int j = 0; j < 4; ++j) gld16((const char*)cbh + go + j * 1024, lh + j * 1024);
#pragma unroll
    for (int j = 0; j < 4; ++j) gld16((const char*)cbl + go + j * 1024, ll + j * 1024);
  };

  const int bxr = (l15 & 7) << 3;

  for (int grp = blockIdx.x >> 2; grp < ngroups; grp += (gridDim.x >> 2)) {
    int base = grp * 64;
    __syncthreads();
    if (t < 64) rows_s[t] = list[min(base + t, n - 1)];
    __syncthreads();
    int rowg = rows_s[w * 16 + l15];

    v8h Ah[8], Al[8];
#pragma unroll
    for (int ks8 = 0; ks8 < 8; ++ks8) {
      const float* p = z + (size_t)rowg * 256 + ks8 * 32 + lhi * 8;
      float4 a = *(const float4*)p, b = *(const float4*)(p + 4);
      v8h hv, lv;
      hv[0] = (_Float16)a.x; lv[0] = (_Float16)(a.x - (float)hv[0]);
      hv[1] = (_Float16)a.y; lv[1] = (_Float16)(a.y - (float)hv[1]);
      hv[2] = (_Float16)a.z; lv[2] = (_Float16)(a.z - (float)hv[2]);
      hv[3] = (_Float16)a.w; lv[3] = (_Float16)(a.w - (float)hv[3]);
      hv[4] = (_Float16)b.x; lv[4] = (_Float16)(b.x - (float)hv[4]);
      hv[5] = (_Float16)b.y; lv[5] = (_Float16)(b.y - (float)hv[5]);
      hv[6] = (_Float16)b.z; lv[6] = (_Float16)(b.z - (float)hv[6]);
      hv[7] = (_Float16)b.w; lv[7] = (_Float16)(b.w - (float)hv[7]);
      Ah[ks8] = hv; Al[ks8] = lv;
    }

    stage2(cq * 8, 0);
    __syncthreads();

    float m1[4], m2[4]; int i1[4];
#pragma unroll
    for (int r = 0; r < 4; ++r) { m1[r] = 3.0e38f; m2[r] = 3.0e38f; i1[r] = 0; }

#pragma unroll
    for (int tnt = 0; tnt < 2; ++tnt) {
      int nt = cq * 2 + tnt;
      float cnv[8];
#pragma unroll
      for (int nf = 0; nf < 8; ++nf) cnv[nf] = cnw[nt * 128 + nf * 16 + l15];

      v4f acc[8];
#pragma unroll
      for (int nf = 0; nf < 8; ++nf) acc[nf] = (v4f){0.f, 0.f, 0.f, 0.f};

      for (int kc = 0; kc < 4; ++kc) {
        int ph = tnt * 4 + kc;            // 0..7
        int g = nt * 4 + kc;
        if (ph < 7) stage2(g + 1, (ph + 1) & 1);
        const short* ch = Ch[ph & 1];
        const short* cl = Cl[ph & 1];
#pragma unroll
        for (int ks = 0; ks < 2; ++ks) {
          int ko = (ks * 32 + lhi * 8) ^ bxr;
          v8h bh[8], bl8[8];
#pragma unroll
          for (int nf = 0; nf < 8; ++nf) {
            int bo = (nf * 16 + l15) * 64 + ko;
            bh[nf]  = *(const v8h*)(ch + bo);
            bl8[nf] = *(const v8h*)(cl + bo);
          }
          v8h ah = Ah[kc * 2 + ks], al = Al[kc * 2 + ks];
#pragma unroll
          for (int nf = 0; nf < 8; ++nf) {
            acc[nf] = __builtin_amdgcn_mfma_f32_16x16x32_f16(al, bh[nf], acc[nf], 0, 0, 0);
            acc[nf] = __builtin_amdgcn_mfma_f32_16x16x32_f16(ah, bl8[nf], acc[nf], 0, 0, 0);
            acc[nf] = __builtin_amdgcn_mfma_f32_16x16x32_f16(ah, bh[nf], acc[nf], 0, 0, 0);
          }
        }
        __syncthreads();
      }

#pragma unroll
      for (int nf = 0; nf < 8; ++nf) {
        int code = nt * 128 + nf * 16 + l15;
#pragma unroll
        for (int r = 0; r < 4; ++r) {
          float s = fmaf(-2.f, acc[nf][r], cnv[nf]);
          m2[r] = fminf(m2[r], fmaxf(m1[r], s));
          bool lt = s < m1[r];
          i1[r] = lt ? code : i1[r];
          m1[r] = lt ? s : m1[r];
        }
      }
    }

#pragma unroll
    for (int off = 1; off < 16; off <<= 1) {
#pragma unroll
      for (int r = 0; r < 4; ++r) {
        float o1 = __shfl_xor(m1[r], off);
        int   oi = __shfl_xor(i1[r], off);
        float o2 = __shfl_xor(m2[r], off);
        bool bb = (o1 < m1[r]) || (o1 == m1[r] && oi < i1[r]);
        float hi = fmaxf(m1[r], o1);
        m2[r] = fminf(hi, fminf(m2[r], o2));
        m1[r] = bb ? o1 : m1[r];
        i1[r] = bb ? oi : i1[r];
      }
    }

    if (l15 == 0) {
#pragma unroll
      for (int r = 0; r < 4; ++r) {
        int fr = w * 16 + lhi * 4 + r;
        int pos = base + fr;
        if (pos < n) {
          pm1[cq * NRMAX + pos] = m1[r];
          pm2[cq * NRMAX + pos] = m2[r];
          pi1[cq * NRMAX + pos] = i1[r];
        }
      }
    }
  }
}

// ---------------- merge: combine 4 code-quarter partials per flagged row ----------------
__global__ __launch_bounds__(256) void vq_merge(
    const int* __restrict__ list, const int* __restrict__ cnt,
    const float* __restrict__ pm1, const float* __restrict__ pm2,
    const int* __restrict__ pi1, int* __restrict__ idx_arr,
    int* __restrict__ list2, int* __restrict__ cnt2) {
  int i = blockIdx.x * 256 + threadIdx.x;
  int n = *cnt;
  if (i >= n) return;
  float m1 = pm1[i], m2 = pm2[i];
  int   i1 = pi1[i];
#pragma unroll
  for (int cq = 1; cq < 4; ++cq) {
    float o1 = pm1[cq * NRMAX + i];
    float o2 = pm2[cq * NRMAX + i];
    int   oi = pi1[cq * NRMAX + i];
    bool bb = (o1 < m1) || (o1 == m1 && oi < i1);
    float hi = fmaxf(m1, o1);
    m2 = fminf(hi, fminf(m2, o2));
    m1 = bb ? o1 : m1;
    i1 = bb ? oi : i1;
  }
  int row = list[i];
  idx_arr[row] = i1;
  if (m2 - m1 < DELTA2) {
    int p = atomicAdd(cnt2, 1);
    list2[p] = row;
  }
}

// ---------------- rescue: exact fp32 recompute (round-1-identical chain) ----------------
__global__ __launch_bounds__(256) void vq_rescue(
    const float* __restrict__ z, const float* __restrict__ cb,
    const float* __restrict__ cnw, const int* __restrict__ list,
    const int* __restrict__ cnt, int* __restrict__ idx_arr) {
  __shared__ float zs[256];
  __shared__ float As;
  __shared__ float wmin[4];
  __shared__ int   widx[4];

  const int t = threadIdx.x;
  const int l = t & 63, w = t >> 6;
  const int n = *cnt;

  for (int i = blockIdx.x; i < n; i += gridDim.x) {
    int row = list[i];
    __syncthreads();
    if (t < 64) ((float4*)zs)[t] = ((const float4*)(z + (size_t)row * DIM))[t];
    __syncthreads();
    if (t < 4) {
      double s = 0.0;
      const float* zz = zs + t * 64;
      for (int d = 0; d < 64; ++d) { float v = zz[d]; s += (double)v * v; }
      s += __shfl_xor(s, 1);
      s += __shfl_xor(s, 2);
      if (t == 0) As = (float)s;
    }
    __syncthreads();
    float Af = As;

    const float4* c0 = (const float4*)(cb + (size_t)(t      ) * DIM);
    const float4* c1 = (const float4*)(cb + (size_t)(t + 256) * DIM);
    const float4* c2 = (const float4*)(cb + (size_t)(t + 512) * DIM);
    const float4* c3 = (const float4*)(cb + (size_t)(t + 768) * DIM);
    float a0 = 0.f, a1 = 0.f, a2 = 0.f, a3 = 0.f;
    for (int d4 = 0; d4 < 64; ++d4) {
      float4 zq = *(const float4*)(zs + d4 * 4);
      float4 va = c0[d4], vb = c1[d4], vc = c2[d4], vd = c3[d4];
      a0 = fmaf(zq.x, va.x, a0); a0 = fmaf(zq.y, va.y, a0);
      a0 = fmaf(zq.z, va.z, a0); a0 = fmaf(zq.w, va.w, a0);
      a1 = fmaf(zq.x, vb.x, a1); a1 = fmaf(zq.y, vb.y, a1);
      a1 = fmaf(zq.z, vb.z, a1); a1 = fmaf(zq.w, vb.w, a1);
      a2 = fmaf(zq.x, vc.x, a2); a2 = fmaf(zq.y, vc.y, a2);
      a2 = fmaf(zq.z, vc.z, a2); a2 = fmaf(zq.w, vc.w, a2);
      a3 = fmaf(zq.x, vd.x, a3); a3 = fmaf(zq.y, vd.y, a3);
      a3 = fmaf(zq.z, vd.z, a3); a3 = fmaf(zq.w, vd.w, a3);
    }
    float accs[4] = {a0, a1, a2, a3};
    float mv = 3.0e38f; int mi = 0;
#pragma unroll
    for (int j = 0; j < 4; ++j) {
      int code = t + j * 256;
      float t1 = fmaf(-2.f, accs[j], Af);
      float t2 = t1 + cnw[code];
      if (t2 < mv) { mv = t2; mi = code; }
    }
#pragma unroll
    for (int off = 1; off < 64; off <<= 1) {
      float ov = __shfl_xor(mv, off);
      int   oi = __shfl_xor(mi, off);
      if (ov < mv || (ov == mv && oi < mi)) { mv = ov; mi = oi; }
    }
    if (l == 0) { wmin[w] = mv; widx[w] = mi; }
    __syncthreads();
    if (t == 0) {
      float bm = wmin[0]; int bi = widx[0];
#pragma unroll
      for (int q = 1; q < 4; ++q)
        if (wmin[q] < bm || (wmin[q] == bm && widx[q] < bi)) { bm = wmin[q]; bi = widx[q]; }
      idx_arr[row] = bi;
    }
    __syncthreads();
  }
}

// ---------------- epilogue: gather, straight-through write, per-block loss ----------------
__global__ __launch_bounds__(256) void vq_epilogue(
    const float* __restrict__ z, const float* __restrict__ cb,
    const int* __restrict__ idx_arr, float* __restrict__ out_q,
    float* __restrict__ out_idx, double* __restrict__ partial) {
  __shared__ int idxs[16];
  __shared__ double lw[4];
  const int t = threadIdx.x;
  const int b0 = blockIdx.x * 16;
  if (t < 16) {
    int k = idx_arr[b0 + t];
    idxs[t] = k;
    out_idx[b0 + t] = (float)k;
  }
  __syncthreads();
  const float4* zb = (const float4*)(z + (size_t)b0 * DIM);
  float4* qb = (float4*)(out_q + (size_t)b0 * DIM);
  double ls = 0.0;
#pragma unroll
  for (int p = 0; p < 4; ++p) {
    int fi = p * 256 + t;
    int ki = idxs[fi >> 6];
    float4 zv = zb[fi];
    float4 cv = ((const float4*)(cb + (size_t)ki * DIM))[fi & 63];
    float dx = cv.x - zv.x, dy = cv.y - zv.y, dz = cv.z - zv.z, dw = cv.w - zv.w;
    float4 o; o.x = zv.x + dx; o.y = zv.y + dy; o.z = zv.z + dz; o.w = zv.w + dw;
    qb[fi] = o;
    ls += (double)dx * dx + (double)dy * dy + (double)dz * dz + (double)dw * dw;
  }
#pragma unroll
  for (int off = 1; off < 64; off <<= 1) ls += __shfl_xor(ls, off);
  if ((t & 63) == 0) lw[t >> 6] = ls;
  __syncthreads();
  if (t == 0) partial[blockIdx.x] = lw[0] + lw[1] + lw[2] + lw[3];
}

// ---------------- finalize losses ----------------
__global__ __launch_bounds__(256) void finalize_kernel(const double* __restrict__ partial,
                                                       float* __restrict__ out_losses) {
  __shared__ double lw[4];
  const int t = threadIdx.x;
  double s = 0.0;
  for (int i = t; i < 4096; i += 256) s += partial[i];
#pragma unroll
  for (int off = 1; off < 64; off <<= 1) s += __shfl_xor(s, off);
  if ((t & 63) == 0) lw[t >> 6] = s;
  __syncthreads();
  if (t == 0) {
    double mse = (lw[0] + lw[1] + lw[2] + lw[3]) / ((double)NROWS * (double)DIM);
    out_losses[0] = (float)(0.25 * mse);  // commitment
    out_losses[1] = (float)mse;           // embedding
  }
}

extern "C" void kernel_launch(void* const* d_in, const int* in_sizes, int n_in,
                              void* d_out, int out_size, void* d_ws, size_t ws_size,
                              hipStream_t stream) {
  const float* z  = (const float*)d_in[0];
  const float* cb = (const float*)d_in[1];
  float* out = (float*)d_out;

  char* ws = (char*)d_ws;
  int*            cnt     = (int*)(ws + 0);
  int*            cnt2    = (int*)(ws + 8);
  float*          cnorm   = (float*)(ws + 4096);
  double*         partial = (double*)(ws + 8192);                 // 4096 doubles -> 40960
  int*            idx_arr = (int*)(ws + 40960);                   // 256KB -> 303104
  int*            list    = (int*)(ws + 303104);                  // 256KB -> 565248
  int*            list2   = (int*)(ws + 565248);                  // 256KB -> 827392
  unsigned short* cbh     = (unsigned short*)(ws + 827392);       // 512KB -> 1351680
  unsigned short* cbl     = (unsigned short*)(ws + 1351680);      // 512KB -> 1875968
  float*          pm1     = (float*)(ws + 1875968);               // 1MB  -> 2924544
  float*          pm2     = (float*)(ws + 2924544);               // 1MB  -> 3973120
  int*            pi1     = (int*)(ws + 3973120);                 // 1MB  -> 5021696

  float* out_q      = out;             // 16777216
  float* out_losses = out + 16777216;  // 2
  float* out_idx    = out + 16777218;  // 65536

  prep_kernel<<<16, 256, 0, stream>>>(cb, cnorm, cbh, cbl, cnt, cnt2);
  vq_mfma<<<NROWS / 128, 256, 0, stream>>>(z, cbh, cnorm, idx_arr, list, cnt);
  vq_refine<<<1024, 256, 0, stream>>>(z, cbh, cbl, cnorm, list, cnt, pm1, pm2, pi1);
  vq_merge<<<NRMAX / 256, 256, 0, stream>>>(list, cnt, pm1, pm2, pi1, idx_arr, list2, cnt2);
  vq_rescue<<<256, 256, 0, stream>>>(z, cb, cnorm, list2, cnt2, idx_arr);
  vq_epilogue<<<NROWS / 16, 256, 0, stream>>>(z, cb, idx_arr, out_q, out_idx, partial);
  finalize_kernel<<<1, 256, 0, stream>>>(partial, out_losses);
}

// Round 19
// 163.361 us; speedup vs baseline: 1.0891x; 1.0891x over previous
//
#include <hip/hip_runtime.h>

#define NROWS  65536
#define DIM    256
#define KCB    1024
#define DELTA  0.012f
#define DELTA2 2.0e-4f
#define NRMAX  65536

typedef __attribute__((ext_vector_type(8))) _Float16 v8h;
typedef __attribute__((ext_vector_type(4))) float v4f;
typedef __attribute__((ext_vector_type(4))) int   v4i;

__device__ __forceinline__ unsigned short h16(float x) {
  _Float16 h = (_Float16)x;                 // v_cvt_f16_f32, RNE
  return __builtin_bit_cast(unsigned short, h);
}
__device__ __forceinline__ unsigned pk2h(float a, float b) {
  return (unsigned)h16(a) | ((unsigned)h16(b) << 16);
}
__device__ __forceinline__ v4i pk8h(float4 a, float4 b) {
  v4i r; r.x = (int)pk2h(a.x,a.y); r.y = (int)pk2h(a.z,a.w);
  r.z = (int)pk2h(b.x,b.y); r.w = (int)pk2h(b.z,b.w);
  return r;
}
__device__ __forceinline__ float f16f(float x) { return (float)(_Float16)x; }
__device__ __forceinline__ void gld16(const void* g, void* l) {
  __builtin_amdgcn_global_load_lds(
      (const __attribute__((address_space(1))) unsigned int*)g,
      (__attribute__((address_space(3))) unsigned int*)l, 16, 0, 0);
}

// ---------------- prep: codebook norms + fp16 hi/lo swizzled-LDS-image codebook ----------------
// layout: [chunk g : 32][code c : 128][k : 64] fp16, k swizzled: pos=(k8*8)^((c&7)<<3)
__global__ __launch_bounds__(256) void prep_kernel(const float* __restrict__ cb,
                                                   float* __restrict__ cnorm,
                                                   unsigned short* __restrict__ cbh,
                                                   unsigned short* __restrict__ cbl,
                                                   int* __restrict__ cnt,
                                                   int* __restrict__ cnt2) {
  int g = blockIdx.x * 256 + threadIdx.x;   // 4096 threads: code k = g>>2, quarter q = g&3
  if (g == 0) { *cnt = 0; *cnt2 = 0; }
  int k = g >> 2, q = g & 3;
  int nt = k >> 7, c = k & 127;
  const float4* row = reinterpret_cast<const float4*>(cb + (size_t)k * DIM) + q * 16;
  size_t off = (size_t)((nt * 4 + q) * 128 + c) * 64;
  unsigned short* dh = cbh + off;
  unsigned short* dl = cbl + off;
  int xr = (c & 7) << 3;
  double s = 0.0;
#pragma unroll
  for (int i = 0; i < 8; ++i) {
    float4 a = row[2 * i], b = row[2 * i + 1];
    s += (double)a.x * a.x + (double)a.y * a.y + (double)a.z * a.z + (double)a.w * a.w;
    s += (double)b.x * b.x + (double)b.y * b.y + (double)b.z * b.z + (double)b.w * b.w;
    *(v4i*)(dh + ((i * 8) ^ xr)) = pk8h(a, b);
    float4 ar, br;
    ar.x = a.x - f16f(a.x); ar.y = a.y - f16f(a.y);
    ar.z = a.z - f16f(a.z); ar.w = a.w - f16f(a.w);
    br.x = b.x - f16f(b.x); br.y = b.y - f16f(b.y);
    br.z = b.z - f16f(b.z); br.w = b.w - f16f(b.w);
    *(v4i*)(dl + ((i * 8) ^ xr)) = pk8h(ar, br);
  }
  s += __shfl_xor(s, 1);
  s += __shfl_xor(s, 2);
  if (q == 0) cnorm[k] = (float)s;
}

// ---------------- stage 1: fp16 MFMA screening (r15 loop verbatim) + appended epilogue ----------------
// Screen loop byte-identical to r15 (VGPR 128, no spill). After the loop, S and
// acc are dead; epilogue tail (register-trivial) writes q/idx/rowloss for this
// block's 128 rows using screen indices. Flagged rows patched later.
__global__ __launch_bounds__(256, 2) void vq_mfma(
    const float* __restrict__ z, const unsigned short* __restrict__ cbh,
    const float* __restrict__ cnw, const float* __restrict__ cb,
    int* __restrict__ idx_arr, int* __restrict__ list, int* __restrict__ cnt,
    float* __restrict__ out_q, float* __restrict__ out_idx,
    float* __restrict__ rowloss) {
  __shared__ __align__(16) short S[32768];   // 64KB: Zs[128][256], then Cs[2][16384]

  const int t = threadIdx.x;
  const int l = t & 63;
  const int w = t >> 6;
  const int l15 = l & 15, lhi = l >> 4;
  const int wm = w * 32;
  const int r0 = blockIdx.x * 128;

#pragma unroll
  for (int p = 0; p < 16; ++p) {
    int u = t + p * 256;
    int row = u >> 5, k8 = u & 31;
    const float4* s = (const float4*)(z + (size_t)(r0 + row) * DIM + k8 * 8);
    float4 a = s[0], b = s[1];
    *(v4i*)(S + row * 256 + ((k8 * 8) ^ ((row & 7) << 3))) = pk8h(a, b);
  }
  __syncthreads();

  v8h A[2][8];
#pragma unroll
  for (int mf = 0; mf < 2; ++mf) {
    int arow = wm + mf * 16 + l15;
    int base = arow * 256, xr = (arow & 7) << 3;
#pragma unroll
    for (int ks8 = 0; ks8 < 8; ++ks8)
      A[mf][ks8] = *(const v8h*)(S + base + ((ks8 * 32 + lhi * 8) ^ xr));
  }
  __syncthreads();   // all A-reads done; S reusable as C double-buffer

  auto stageC = [&](int p) {   // stage 32KB chunk-pair p into half (p&1)
    const char* gb = (const char*)cbh + (size_t)p * 32768 + w * 8192 + l * 16;
    char* lb = (char*)(S + (p & 1) * 16384) + w * 8192;
#pragma unroll
    for (int j = 0; j < 8; ++j) gld16(gb + j * 1024, lb + j * 1024);
  };

  int bcode[8], boff[8], bxr[8];
#pragma unroll
  for (int nf = 0; nf < 8; ++nf) {
    bcode[nf] = nf * 16 + l15;
    boff[nf] = bcode[nf] * 64;
    bxr[nf] = (bcode[nf] & 7) << 3;
  }

  float m1[8], m2[8]; int i1[8];
#pragma unroll
  for (int sl = 0; sl < 8; ++sl) { m1[sl] = 3.0e38f; m2[sl] = 3.0e38f; i1[sl] = 0; }

  stageC(0);
  __syncthreads();

  for (int nt = 0; nt < 8; ++nt) {
    float cnv[8];
#pragma unroll
    for (int nf = 0; nf < 8; ++nf) cnv[nf] = cnw[nt * 128 + bcode[nf]];

    v4f acc[2][8];
#pragma unroll
    for (int mf = 0; mf < 2; ++mf)
#pragma unroll
      for (int nf = 0; nf < 8; ++nf) acc[mf][nf] = (v4f){0.f, 0.f, 0.f, 0.f};

    for (int kh = 0; kh < 2; ++kh) {
      int p = nt * 2 + kh;
      if (p < 15) stageC(p + 1);   // prefetch next pair ∥ compute
      const short* cur = S + (p & 1) * 16384;
#pragma unroll
      for (int ks = 0; ks < 4; ++ks) {
        int sub = (ks >> 1) * 8192;
        int ko = (ks & 1) * 32 + lhi * 8;
        v8h b[8];
#pragma unroll
        for (int nf = 0; nf < 8; ++nf)
          b[nf] = *(const v8h*)(cur + sub + boff[nf] + (ko ^ bxr[nf]));
#pragma unroll
        for (int mf = 0; mf < 2; ++mf)
#pragma unroll
          for (int nf = 0; nf < 8; ++nf)
            acc[mf][nf] = __builtin_amdgcn_mfma_f32_16x16x32_f16(A[mf][kh * 4 + ks], b[nf], acc[mf][nf], 0, 0, 0);
      }
      __syncthreads();
    }

#pragma unroll
    for (int mf = 0; mf < 2; ++mf)
#pragma unroll
      for (int nf = 0; nf < 8; ++nf) {
        int code = nt * 128 + bcode[nf];
#pragma unroll
        for (int r = 0; r < 4; ++r) {
          float s = fmaf(-2.f, acc[mf][nf][r], cnv[nf]);
          int sl = mf * 4 + r;
          m2[sl] = fminf(m2[sl], fmaxf(m1[sl], s));
          bool lt = s < m1[sl];
          i1[sl] = lt ? code : i1[sl];
          m1[sl] = lt ? s : m1[sl];
        }
      }
  }

#pragma unroll
  for (int off = 1; off < 16; off <<= 1) {
#pragma unroll
    for (int sl = 0; sl < 8; ++sl) {
      float o1 = __shfl_xor(m1[sl], off);
      int   oi = __shfl_xor(i1[sl], off);
      float o2 = __shfl_xor(m2[sl], off);
      bool bb = (o1 < m1[sl]) || (o1 == m1[sl] && oi < i1[sl]);
      float hi = fmaxf(m1[sl], o1);
      m2[sl] = fminf(hi, fminf(m2[sl], o2));
      m1[sl] = bb ? o1 : m1[sl];
      i1[sl] = bb ? oi : i1[sl];
    }
  }

  int* idxS = (int*)S;   // S dead after loop; reuse for idx broadcast
  if (l15 == 0) {
#pragma unroll
    for (int sl = 0; sl < 8; ++sl) {
      int row = wm + (sl >> 2) * 16 + lhi * 4 + (sl & 3);
      idx_arr[r0 + row] = i1[sl];
      out_idx[r0 + row] = (float)i1[sl];
      idxS[row] = i1[sl];
      if (m2[sl] - m1[sl] < DELTA) {
        int p = atomicAdd(cnt, 1);
        list[p] = r0 + row;
      }
    }
  }
  __syncthreads();

  // appended epilogue: wave w handles rows p*4+w; 1KB coalesced per wave-iter
  for (int p = 0; p < 32; ++p) {
    int row = p * 4 + w;
    int k = idxS[row];
    float4 zv = ((const float4*)(z + (size_t)(r0 + row) * DIM))[l];
    float4 cv = ((const float4*)(cb + (size_t)k * DIM))[l];
    float dx = cv.x - zv.x, dy = cv.y - zv.y, dz = cv.z - zv.z, dw = cv.w - zv.w;
    float4 o; o.x = zv.x + dx; o.y = zv.y + dy; o.z = zv.z + dz; o.w = zv.w + dw;
    ((float4*)(out_q + (size_t)(r0 + row) * DIM))[l] = o;
    double ls = (double)dx * dx + (double)dy * dy + (double)dz * dz + (double)dw * dw;
#pragma unroll
    for (int off = 1; off < 64; off <<= 1) ls += __shfl_xor(ls, off);
    if (l == 0) rowloss[r0 + row] = (float)ls;
  }
}

// ---------------- stage 2: split-fp16 refine, code-quarter split (r15 verbatim, (256,1)) ----------------
__global__ __launch_bounds__(256, 1) void vq_refine(
    const float* __restrict__ z,
    const unsigned short* __restrict__ cbh, const unsigned short* __restrict__ cbl,
    const float* __restrict__ cnw, const int* __restrict__ list,
    const int* __restrict__ cnt,
    float* __restrict__ pm1, float* __restrict__ pm2, int* __restrict__ pi1) {
  __shared__ __align__(16) short Ch[2][8192];  // 2 x 16KB
  __shared__ __align__(16) short Cl[2][8192];  // 2 x 16KB
  __shared__ int rows_s[64];

  const int t = threadIdx.x;
  const int l = t & 63, w = t >> 6;
  const int l15 = l & 15, lhi = l >> 4;
  const int n = *cnt;
  const int ngroups = (n + 63) >> 6;
  const int cq = blockIdx.x & 3;

  auto stage2 = [&](int g, int buf) {
    size_t go = (size_t)g * 16384 + w * 4096 + l * 16;
    char* lh = (char*)Ch[buf] + w * 4096;
    char* ll = (char*)Cl[buf] + w * 4096;
#pragma unroll
    for (int j = 0; j < 4; ++j) gld16((const char*)cbh + go + j * 1024, lh + j * 1024);
#pragma unroll
    for (int j = 0; j < 4; ++j) gld16((const char*)cbl + go + j * 1024, ll + j * 1024);
  };

  const int bxr = (l15 & 7) << 3;

  for (int grp = blockIdx.x >> 2; grp < ngroups; grp += (gridDim.x >> 2)) {
    int base = grp * 64;
    __syncthreads();
    if (t < 64) rows_s[t] = list[min(base + t, n - 1)];
    __syncthreads();
    int rowg = rows_s[w * 16 + l15];

    v8h Ah[8], Al[8];
#pragma unroll
    for (int ks8 = 0; ks8 < 8; ++ks8) {
      const float* p = z + (size_t)rowg * 256 + ks8 * 32 + lhi * 8;
      float4 a = *(const float4*)p, b = *(const float4*)(p + 4);
      v8h hv, lv;
      hv[0] = (_Float16)a.x; lv[0] = (_Float16)(a.x - (float)hv[0]);
      hv[1] = (_Float16)a.y; lv[1] = (_Float16)(a.y - (float)hv[1]);
      hv[2] = (_Float16)a.z; lv[2] = (_Float16)(a.z - (float)hv[2]);
      hv[3] = (_Float16)a.w; lv[3] = (_Float16)(a.w - (float)hv[3]);
      hv[4] = (_Float16)b.x; lv[4] = (_Float16)(b.x - (float)hv[4]);
      hv[5] = (_Float16)b.y; lv[5] = (_Float16)(b.y - (float)hv[5]);
      hv[6] = (_Float16)b.z; lv[6] = (_Float16)(b.z - (float)hv[6]);
      hv[7] = (_Float16)b.w; lv[7] = (_Float16)(b.w - (float)hv[7]);
      Ah[ks8] = hv; Al[ks8] = lv;
    }

    stage2(cq * 8, 0);
    __syncthreads();

    float m1[4], m2[4]; int i1[4];
#pragma unroll
    for (int r = 0; r < 4; ++r) { m1[r] = 3.0e38f; m2[r] = 3.0e38f; i1[r] = 0; }

#pragma unroll
    for (int tnt = 0; tnt < 2; ++tnt) {
      int nt = cq * 2 + tnt;
      float cnv[8];
#pragma unroll
      for (int nf = 0; nf < 8; ++nf) cnv[nf] = cnw[nt * 128 + nf * 16 + l15];

      v4f acc[8];
#pragma unroll
      for (int nf = 0; nf < 8; ++nf) acc[nf] = (v4f){0.f, 0.f, 0.f, 0.f};

      for (int kc = 0; kc < 4; ++kc) {
        int ph = tnt * 4 + kc;            // 0..7
        int g = nt * 4 + kc;
        if (ph < 7) stage2(g + 1, (ph + 1) & 1);
        const short* ch = Ch[ph & 1];
        const short* cl = Cl[ph & 1];
#pragma unroll
        for (int ks = 0; ks < 2; ++ks) {
          int ko = (ks * 32 + lhi * 8) ^ bxr;
          v8h bh[8], bl8[8];
#pragma unroll
          for (int nf = 0; nf < 8; ++nf) {
            int bo = (nf * 16 + l15) * 64 + ko;
            bh[nf]  = *(const v8h*)(ch + bo);
            bl8[nf] = *(const v8h*)(cl + bo);
          }
          v8h ah = Ah[kc * 2 + ks], al = Al[kc * 2 + ks];
#pragma unroll
          for (int nf = 0; nf < 8; ++nf) {
            acc[nf] = __builtin_amdgcn_mfma_f32_16x16x32_f16(al, bh[nf], acc[nf], 0, 0, 0);
            acc[nf] = __builtin_amdgcn_mfma_f32_16x16x32_f16(ah, bl8[nf], acc[nf], 0, 0, 0);
            acc[nf] = __builtin_amdgcn_mfma_f32_16x16x32_f16(ah, bh[nf], acc[nf], 0, 0, 0);
          }
        }
        __syncthreads();
      }

#pragma unroll
      for (int nf = 0; nf < 8; ++nf) {
        int code = nt * 128 + nf * 16 + l15;
#pragma unroll
        for (int r = 0; r < 4; ++r) {
          float s = fmaf(-2.f, acc[nf][r], cnv[nf]);
          m2[r] = fminf(m2[r], fmaxf(m1[r], s));
          bool lt = s < m1[r];
          i1[r] = lt ? code : i1[r];
          m1[r] = lt ? s : m1[r];
        }
      }
    }

#pragma unroll
    for (int off = 1; off < 16; off <<= 1) {
#pragma unroll
      for (int r = 0; r < 4; ++r) {
        float o1 = __shfl_xor(m1[r], off);
        int   oi = __shfl_xor(i1[r], off);
        float o2 = __shfl_xor(m2[r], off);
        bool bb = (o1 < m1[r]) || (o1 == m1[r] && oi < i1[r]);
        float hi = fmaxf(m1[r], o1);
        m2[r] = fminf(hi, fminf(m2[r], o2));
        m1[r] = bb ? o1 : m1[r];
        i1[r] = bb ? oi : i1[r];
      }
    }

    if (l15 == 0) {
#pragma unroll
      for (int r = 0; r < 4; ++r) {
        int fr = w * 16 + lhi * 4 + r;
        int pos = base + fr;
        if (pos < n) {
          pm1[cq * NRMAX + pos] = m1[r];
          pm2[cq * NRMAX + pos] = m2[r];
          pi1[cq * NRMAX + pos] = i1[r];
        }
      }
    }
  }
}

// ---------------- merge: combine 4 code-quarter partials per flagged row ----------------
__global__ __launch_bounds__(256) void vq_merge(
    const int* __restrict__ list, const int* __restrict__ cnt,
    const float* __restrict__ pm1, const float* __restrict__ pm2,
    const int* __restrict__ pi1, int* __restrict__ idx_arr,
    int* __restrict__ list2, int* __restrict__ cnt2) {
  int i = blockIdx.x * 256 + threadIdx.x;
  int n = *cnt;
  if (i >= n) return;
  float m1 = pm1[i], m2 = pm2[i];
  int   i1 = pi1[i];
#pragma unroll
  for (int cq = 1; cq < 4; ++cq) {
    float o1 = pm1[cq * NRMAX + i];
    float o2 = pm2[cq * NRMAX + i];
    int   oi = pi1[cq * NRMAX + i];
    bool bb = (o1 < m1) || (o1 == m1 && oi < i1);
    float hi = fmaxf(m1, o1);
    m2 = fminf(hi, fminf(m2, o2));
    m1 = bb ? o1 : m1;
    i1 = bb ? oi : i1;
  }
  int row = list[i];
  idx_arr[row] = i1;
  if (m2 - m1 < DELTA2) {
    int p = atomicAdd(cnt2, 1);
    list2[p] = row;
  }
}

// ---------------- rescue: exact fp32 recompute (round-1-identical chain) ----------------
__global__ __launch_bounds__(256) void vq_rescue(
    const float* __restrict__ z, const float* __restrict__ cb,
    const float* __restrict__ cnw, const int* __restrict__ list,
    const int* __restrict__ cnt, int* __restrict__ idx_arr) {
  __shared__ float zs[256];
  __shared__ float As;
  __shared__ float wmin[4];
  __shared__ int   widx[4];

  const int t = threadIdx.x;
  const int l = t & 63, w = t >> 6;
  const int n = *cnt;

  for (int i = blockIdx.x; i < n; i += gridDim.x) {
    int row = list[i];
    __syncthreads();
    if (t < 64) ((float4*)zs)[t] = ((const float4*)(z + (size_t)row * DIM))[t];
    __syncthreads();
    if (t < 4) {
      double s = 0.0;
      const float* zz = zs + t * 64;
      for (int d = 0; d < 64; ++d) { float v = zz[d]; s += (double)v * v; }
      s += __shfl_xor(s, 1);
      s += __shfl_xor(s, 2);
      if (t == 0) As = (float)s;
    }
    __syncthreads();
    float Af = As;

    const float4* c0 = (const float4*)(cb + (size_t)(t      ) * DIM);
    const float4* c1 = (const float4*)(cb + (size_t)(t + 256) * DIM);
    const float4* c2 = (const float4*)(cb + (size_t)(t + 512) * DIM);
    const float4* c3 = (const float4*)(cb + (size_t)(t + 768) * DIM);
    float a0 = 0.f, a1 = 0.f, a2 = 0.f, a3 = 0.f;
    for (int d4 = 0; d4 < 64; ++d4) {
      float4 zq = *(const float4*)(zs + d4 * 4);
      float4 va = c0[d4], vb = c1[d4], vc = c2[d4], vd = c3[d4];
      a0 = fmaf(zq.x, va.x, a0); a0 = fmaf(zq.y, va.y, a0);
      a0 = fmaf(zq.z, va.z, a0); a0 = fmaf(zq.w, va.w, a0);
      a1 = fmaf(zq.x, vb.x, a1); a1 = fmaf(zq.y, vb.y, a1);
      a1 = fmaf(zq.z, vb.z, a1); a1 = fmaf(zq.w, vb.w, a1);
      a2 = fmaf(zq.x, vc.x, a2); a2 = fmaf(zq.y, vc.y, a2);
      a2 = fmaf(zq.z, vc.z, a2); a2 = fmaf(zq.w, vc.w, a2);
      a3 = fmaf(zq.x, vd.x, a3); a3 = fmaf(zq.y, vd.y, a3);
      a3 = fmaf(zq.z, vd.z, a3); a3 = fmaf(zq.w, vd.w, a3);
    }
    float accs[4] = {a0, a1, a2, a3};
    float mv = 3.0e38f; int mi = 0;
#pragma unroll
    for (int j = 0; j < 4; ++j) {
      int code = t + j * 256;
      float t1 = fmaf(-2.f, accs[j], Af);
      float t2 = t1 + cnw[code];
      if (t2 < mv) { mv = t2; mi = code; }
    }
#pragma unroll
    for (int off = 1; off < 64; off <<= 1) {
      float ov = __shfl_xor(mv, off);
      int   oi = __shfl_xor(mi, off);
      if (ov < mv || (ov == mv && oi < mi)) { mv = ov; mi = oi; }
    }
    if (l == 0) { wmin[w] = mv; widx[w] = mi; }
    __syncthreads();
    if (t == 0) {
      float bm = wmin[0]; int bi = widx[0];
#pragma unroll
      for (int q = 1; q < 4; ++q)
        if (wmin[q] < bm || (wmin[q] == bm && widx[q] < bi)) { bm = wmin[q]; bi = widx[q]; }
      idx_arr[row] = bi;
    }
    __syncthreads();
  }
}

// ---------------- patch: rewrite q/loss/idx for flagged rows with final indices ----------------
__global__ __launch_bounds__(64) void vq_patch(
    const float* __restrict__ z, const float* __restrict__ cb,
    const int* __restrict__ list, const int* __restrict__ cnt,
    const int* __restrict__ idx_arr, float* __restrict__ out_q,
    float* __restrict__ out_idx, float* __restrict__ rowloss) {
  const int l = threadIdx.x;
  const int n = *cnt;
  for (int i = blockIdx.x; i < n; i += gridDim.x) {
    int row = list[i];
    int k = idx_arr[row];
    float4 zv = ((const float4*)(z + (size_t)row * DIM))[l];
    float4 cv = ((const float4*)(cb + (size_t)k * DIM))[l];
    float dx = cv.x - zv.x, dy = cv.y - zv.y, dz = cv.z - zv.z, dw = cv.w - zv.w;
    float4 o; o.x = zv.x + dx; o.y = zv.y + dy; o.z = zv.z + dz; o.w = zv.w + dw;
    ((float4*)(out_q + (size_t)row * DIM))[l] = o;
    double ls = (double)dx * dx + (double)dy * dy + (double)dz * dz + (double)dw * dw;
#pragma unroll
    for (int off = 1; off < 64; off <<= 1) ls += __shfl_xor(ls, off);
    if (l == 0) { rowloss[row] = (float)ls; out_idx[row] = (float)k; }
  }
}

// ---------------- finalize losses ----------------
__global__ __launch_bounds__(256) void finalize_kernel(const float* __restrict__ rowloss,
                                                       float* __restrict__ out_losses) {
  __shared__ double lw[4];
  const int t = threadIdx.x;
  double s = 0.0;
  for (int i = t; i < NROWS / 4; i += 256) {
    float4 v = ((const float4*)rowloss)[i];
    s += (double)v.x + (double)v.y + (double)v.z + (double)v.w;
  }
#pragma unroll
  for (int off = 1; off < 64; off <<= 1) s += __shfl_xor(s, off);
  if ((t & 63) == 0) lw[t >> 6] = s;
  __syncthreads();
  if (t == 0) {
    double mse = (lw[0] + lw[1] + lw[2] + lw[3]) / ((double)NROWS * (double)DIM);
    out_losses[0] = (float)(0.25 * mse);  // commitment
    out_losses[1] = (float)mse;           // embedding
  }
}

extern "C" void kernel_launch(void* const* d_in, const int* in_sizes, int n_in,
                              void* d_out, int out_size, void* d_ws, size_t ws_size,
                              hipStream_t stream) {
  const float* z  = (const float*)d_in[0];
  const float* cb = (const float*)d_in[1];
  float* out = (float*)d_out;

  char* ws = (char*)d_ws;
  int*            cnt     = (int*)(ws + 0);
  int*            cnt2    = (int*)(ws + 8);
  float*          cnorm   = (float*)(ws + 4096);                  // 4KB
  float*          rowloss = (float*)(ws + 8192);                  // 256KB -> 270336
  int*            idx_arr = (int*)(ws + 270336);                  // 256KB -> 532480
  int*            list    = (int*)(ws + 532480);                  // 256KB -> 794624
  int*            list2   = (int*)(ws + 794624);                  // 256KB -> 1056768
  unsigned short* cbh     = (unsigned short*)(ws + 1056768);      // 512KB -> 1581056
  unsigned short* cbl     = (unsigned short*)(ws + 1581056);      // 512KB -> 2105344
  float*          pm1     = (float*)(ws + 2105344);               // 1MB -> 3153920
  float*          pm2     = (float*)(ws + 3153920);               // 1MB -> 4202496
  int*            pi1     = (int*)(ws + 4202496);                 // 1MB -> 5251072

  float* out_q      = out;             // 16777216
  float* out_losses = out + 16777216;  // 2
  float* out_idx    = out + 16777218;  // 65536

  prep_kernel<<<16, 256, 0, stream>>>(cb, cnorm, cbh, cbl, cnt, cnt2);
  vq_mfma<<<NROWS / 128, 256, 0, stream>>>(z, cbh, cnorm, cb, idx_arr, list, cnt,
                                           out_q, out_idx, rowloss);
  vq_refine<<<1024, 256, 0, stream>>>(z, cbh, cbl, cnorm, list, cnt, pm1, pm2, pi1);
  vq_merge<<<NRMAX / 256, 256, 0, stream>>>(list, cnt, pm1, pm2, pi1, idx_arr, list2, cnt2);
  vq_rescue<<<256, 256, 0, stream>>>(z, cb, cnorm, list2, cnt2, idx_arr);
  vq_patch<<<1024, 64, 0, stream>>>(z, cb, list, cnt, idx_arr, out_q, out_idx, rowloss);
  finalize_kernel<<<1, 256, 0, stream>>>(rowloss, out_losses);
}

// Round 20
// 145.090 us; speedup vs baseline: 1.2263x; 1.1259x over previous
//
#include <hip/hip_runtime.h>

#define NROWS  65536
#define DIM    256
#define KCB    1024
#define DELTA  0.012f
#define DELTA2 2.0e-4f
#define NRMAX  65536

typedef __attribute__((ext_vector_type(8))) _Float16 v8h;
typedef __attribute__((ext_vector_type(4))) float v4f;
typedef __attribute__((ext_vector_type(4))) int   v4i;

__device__ __forceinline__ unsigned short h16(float x) {
  _Float16 h = (_Float16)x;                 // v_cvt_f16_f32, RNE
  return __builtin_bit_cast(unsigned short, h);
}
__device__ __forceinline__ unsigned pk2h(float a, float b) {
  return (unsigned)h16(a) | ((unsigned)h16(b) << 16);
}
__device__ __forceinline__ v4i pk8h(float4 a, float4 b) {
  v4i r; r.x = (int)pk2h(a.x,a.y); r.y = (int)pk2h(a.z,a.w);
  r.z = (int)pk2h(b.x,b.y); r.w = (int)pk2h(b.z,b.w);
  return r;
}
__device__ __forceinline__ float f16f(float x) { return (float)(_Float16)x; }
__device__ __forceinline__ void gld16(const void* g, void* l) {
  __builtin_amdgcn_global_load_lds(
      (const __attribute__((address_space(1))) unsigned int*)g,
      (__attribute__((address_space(3))) unsigned int*)l, 16, 0, 0);
}

// ---------------- prep: codebook norms + fp16 hi/lo swizzled-LDS-image codebook ----------------
// layout: [chunk g : 32][code c : 128][k : 64] fp16, k swizzled: pos=(k8*8)^((c&7)<<3)
__global__ __launch_bounds__(256) void prep_kernel(const float* __restrict__ cb,
                                                   float* __restrict__ cnorm,
                                                   unsigned short* __restrict__ cbh,
                                                   unsigned short* __restrict__ cbl,
                                                   int* __restrict__ cnt,
                                                   int* __restrict__ cnt2) {
  int g = blockIdx.x * 256 + threadIdx.x;   // 4096 threads: code k = g>>2, quarter q = g&3
  if (g == 0) { *cnt = 0; *cnt2 = 0; }
  int k = g >> 2, q = g & 3;
  int nt = k >> 7, c = k & 127;
  const float4* row = reinterpret_cast<const float4*>(cb + (size_t)k * DIM) + q * 16;
  size_t off = (size_t)((nt * 4 + q) * 128 + c) * 64;
  unsigned short* dh = cbh + off;
  unsigned short* dl = cbl + off;
  int xr = (c & 7) << 3;
  double s = 0.0;
#pragma unroll
  for (int i = 0; i < 8; ++i) {
    float4 a = row[2 * i], b = row[2 * i + 1];
    s += (double)a.x * a.x + (double)a.y * a.y + (double)a.z * a.z + (double)a.w * a.w;
    s += (double)b.x * b.x + (double)b.y * b.y + (double)b.z * b.z + (double)b.w * b.w;
    *(v4i*)(dh + ((i * 8) ^ xr)) = pk8h(a, b);
    float4 ar, br;
    ar.x = a.x - f16f(a.x); ar.y = a.y - f16f(a.y);
    ar.z = a.z - f16f(a.z); ar.w = a.w - f16f(a.w);
    br.x = b.x - f16f(b.x); br.y = b.y - f16f(b.y);
    br.z = b.z - f16f(b.z); br.w = b.w - f16f(b.w);
    *(v4i*)(dl + ((i * 8) ^ xr)) = pk8h(ar, br);
  }
  s += __shfl_xor(s, 1);
  s += __shfl_xor(s, 2);
  if (q == 0) cnorm[k] = (float)s;
}

// ---------------- stage 1: fp16 MFMA screening (r15 verbatim + T5 setprio) ----------------
__global__ __launch_bounds__(256, 2) void vq_mfma(
    const float* __restrict__ z, const unsigned short* __restrict__ cbh,
    const float* __restrict__ cnw, int* __restrict__ idx_arr,
    int* __restrict__ list, int* __restrict__ cnt) {
  __shared__ __align__(16) short S[32768];   // 64KB: Zs[128][256], then Cs[2][16384]

  const int t = threadIdx.x;
  const int l = t & 63;
  const int w = t >> 6;
  const int l15 = l & 15, lhi = l >> 4;
  const int wm = w * 32;
  const int r0 = blockIdx.x * 128;

#pragma unroll
  for (int p = 0; p < 16; ++p) {
    int u = t + p * 256;
    int row = u >> 5, k8 = u & 31;
    const float4* s = (const float4*)(z + (size_t)(r0 + row) * DIM + k8 * 8);
    float4 a = s[0], b = s[1];
    *(v4i*)(S + row * 256 + ((k8 * 8) ^ ((row & 7) << 3))) = pk8h(a, b);
  }
  __syncthreads();

  v8h A[2][8];
#pragma unroll
  for (int mf = 0; mf < 2; ++mf) {
    int arow = wm + mf * 16 + l15;
    int base = arow * 256, xr = (arow & 7) << 3;
#pragma unroll
    for (int ks8 = 0; ks8 < 8; ++ks8)
      A[mf][ks8] = *(const v8h*)(S + base + ((ks8 * 32 + lhi * 8) ^ xr));
  }
  __syncthreads();   // all A-reads done; S reusable as C double-buffer

  auto stageC = [&](int p) {   // stage 32KB chunk-pair p into half (p&1)
    const char* gb = (const char*)cbh + (size_t)p * 32768 + w * 8192 + l * 16;
    char* lb = (char*)(S + (p & 1) * 16384) + w * 8192;
#pragma unroll
    for (int j = 0; j < 8; ++j) gld16(gb + j * 1024, lb + j * 1024);
  };

  int bcode[8], boff[8], bxr[8];
#pragma unroll
  for (int nf = 0; nf < 8; ++nf) {
    bcode[nf] = nf * 16 + l15;
    boff[nf] = bcode[nf] * 64;
    bxr[nf] = (bcode[nf] & 7) << 3;
  }

  float m1[8], m2[8]; int i1[8];
#pragma unroll
  for (int sl = 0; sl < 8; ++sl) { m1[sl] = 3.0e38f; m2[sl] = 3.0e38f; i1[sl] = 0; }

  stageC(0);
  __syncthreads();

  for (int nt = 0; nt < 8; ++nt) {
    float cnv[8];
#pragma unroll
    for (int nf = 0; nf < 8; ++nf) cnv[nf] = cnw[nt * 128 + bcode[nf]];

    v4f acc[2][8];
#pragma unroll
    for (int mf = 0; mf < 2; ++mf)
#pragma unroll
      for (int nf = 0; nf < 8; ++nf) acc[mf][nf] = (v4f){0.f, 0.f, 0.f, 0.f};

    for (int kh = 0; kh < 2; ++kh) {
      int p = nt * 2 + kh;
      if (p < 15) stageC(p + 1);   // prefetch next pair ∥ compute
      const short* cur = S + (p & 1) * 16384;
      __builtin_amdgcn_s_setprio(1);   // T5: favor this wave's MFMA cluster
#pragma unroll
      for (int ks = 0; ks < 4; ++ks) {
        int sub = (ks >> 1) * 8192;
        int ko = (ks & 1) * 32 + lhi * 8;
        v8h b[8];
#pragma unroll
        for (int nf = 0; nf < 8; ++nf)
          b[nf] = *(const v8h*)(cur + sub + boff[nf] + (ko ^ bxr[nf]));
#pragma unroll
        for (int mf = 0; mf < 2; ++mf)
#pragma unroll
          for (int nf = 0; nf < 8; ++nf)
            acc[mf][nf] = __builtin_amdgcn_mfma_f32_16x16x32_f16(A[mf][kh * 4 + ks], b[nf], acc[mf][nf], 0, 0, 0);
      }
      __builtin_amdgcn_s_setprio(0);
      __syncthreads();
    }

#pragma unroll
    for (int mf = 0; mf < 2; ++mf)
#pragma unroll
      for (int nf = 0; nf < 8; ++nf) {
        int code = nt * 128 + bcode[nf];
#pragma unroll
        for (int r = 0; r < 4; ++r) {
          float s = fmaf(-2.f, acc[mf][nf][r], cnv[nf]);
          int sl = mf * 4 + r;
          m2[sl] = fminf(m2[sl], fmaxf(m1[sl], s));
          bool lt = s < m1[sl];
          i1[sl] = lt ? code : i1[sl];
          m1[sl] = lt ? s : m1[sl];
        }
      }
  }

#pragma unroll
  for (int off = 1; off < 16; off <<= 1) {
#pragma unroll
    for (int sl = 0; sl < 8; ++sl) {
      float o1 = __shfl_xor(m1[sl], off);
      int   oi = __shfl_xor(i1[sl], off);
      float o2 = __shfl_xor(m2[sl], off);
      bool bb = (o1 < m1[sl]) || (o1 == m1[sl] && oi < i1[sl]);
      float hi = fmaxf(m1[sl], o1);
      m2[sl] = fminf(hi, fminf(m2[sl], o2));
      m1[sl] = bb ? o1 : m1[sl];
      i1[sl] = bb ? oi : i1[sl];
    }
  }

  if (l15 == 0) {
#pragma unroll
    for (int sl = 0; sl < 8; ++sl) {
      int row = wm + (sl >> 2) * 16 + lhi * 4 + (sl & 3);
      idx_arr[r0 + row] = i1[sl];
      if (m2[sl] - m1[sl] < DELTA) {
        int p = atomicAdd(cnt, 1);
        list[p] = r0 + row;
      }
    }
  }
}

// ---------------- stage 2: split-fp16 refine, code-quarter split (r15 verbatim, (256,1)) ----------------
__global__ __launch_bounds__(256, 1) void vq_refine(
    const float* __restrict__ z,
    const unsigned short* __restrict__ cbh, const unsigned short* __restrict__ cbl,
    const float* __restrict__ cnw, const int* __restrict__ list,
    const int* __restrict__ cnt,
    float* __restrict__ pm1, float* __restrict__ pm2, int* __restrict__ pi1) {
  __shared__ __align__(16) short Ch[2][8192];  // 2 x 16KB
  __shared__ __align__(16) short Cl[2][8192];  // 2 x 16KB
  __shared__ int rows_s[64];

  const int t = threadIdx.x;
  const int l = t & 63, w = t >> 6;
  const int l15 = l & 15, lhi = l >> 4;
  const int n = *cnt;
  const int ngroups = (n + 63) >> 6;
  const int cq = blockIdx.x & 3;

  auto stage2 = [&](int g, int buf) {
    size_t go = (size_t)g * 16384 + w * 4096 + l * 16;
    char* lh = (char*)Ch[buf] + w * 4096;
    char* ll = (char*)Cl[buf] + w * 4096;
#pragma unroll
    for (int j = 0; j < 4; ++j) gld16((const char*)cbh + go + j * 1024, lh + j * 1024);
#pragma unroll
    for (int j = 0; j < 4; ++j) gld16((const char*)cbl + go + j * 1024, ll + j * 1024);
  };

  const int bxr = (l15 & 7) << 3;

  for (int grp = blockIdx.x >> 2; grp < ngroups; grp += (gridDim.x >> 2)) {
    int base = grp * 64;
    __syncthreads();
    if (t < 64) rows_s[t] = list[min(base + t, n - 1)];
    __syncthreads();
    int rowg = rows_s[w * 16 + l15];

    v8h Ah[8], Al[8];
#pragma unroll
    for (int ks8 = 0; ks8 < 8; ++ks8) {
      const float* p = z + (size_t)rowg * 256 + ks8 * 32 + lhi * 8;
      float4 a = *(const float4*)p, b = *(const float4*)(p + 4);
      v8h hv, lv;
      hv[0] = (_Float16)a.x; lv[0] = (_Float16)(a.x - (float)hv[0]);
      hv[1] = (_Float16)a.y; lv[1] = (_Float16)(a.y - (float)hv[1]);
      hv[2] = (_Float16)a.z; lv[2] = (_Float16)(a.z - (float)hv[2]);
      hv[3] = (_Float16)a.w; lv[3] = (_Float16)(a.w - (float)hv[3]);
      hv[4] = (_Float16)b.x; lv[4] = (_Float16)(b.x - (float)hv[4]);
      hv[5] = (_Float16)b.y; lv[5] = (_Float16)(b.y - (float)hv[5]);
      hv[6] = (_Float16)b.z; lv[6] = (_Float16)(b.z - (float)hv[6]);
      hv[7] = (_Float16)b.w; lv[7] = (_Float16)(b.w - (float)hv[7]);
      Ah[ks8] = hv; Al[ks8] = lv;
    }

    stage2(cq * 8, 0);
    __syncthreads();

    float m1[4], m2[4]; int i1[4];
#pragma unroll
    for (int r = 0; r < 4; ++r) { m1[r] = 3.0e38f; m2[r] = 3.0e38f; i1[r] = 0; }

#pragma unroll
    for (int tnt = 0; tnt < 2; ++tnt) {
      int nt = cq * 2 + tnt;
      float cnv[8];
#pragma unroll
      for (int nf = 0; nf < 8; ++nf) cnv[nf] = cnw[nt * 128 + nf * 16 + l15];

      v4f acc[8];
#pragma unroll
      for (int nf = 0; nf < 8; ++nf) acc[nf] = (v4f){0.f, 0.f, 0.f, 0.f};

      for (int kc = 0; kc < 4; ++kc) {
        int ph = tnt * 4 + kc;            // 0..7
        int g = nt * 4 + kc;
        if (ph < 7) stage2(g + 1, (ph + 1) & 1);
        const short* ch = Ch[ph & 1];
        const short* cl = Cl[ph & 1];
#pragma unroll
        for (int ks = 0; ks < 2; ++ks) {
          int ko = (ks * 32 + lhi * 8) ^ bxr;
          v8h bh[8], bl8[8];
#pragma unroll
          for (int nf = 0; nf < 8; ++nf) {
            int bo = (nf * 16 + l15) * 64 + ko;
            bh[nf]  = *(const v8h*)(ch + bo);
            bl8[nf] = *(const v8h*)(cl + bo);
          }
          v8h ah = Ah[kc * 2 + ks], al = Al[kc * 2 + ks];
#pragma unroll
          for (int nf = 0; nf < 8; ++nf) {
            acc[nf] = __builtin_amdgcn_mfma_f32_16x16x32_f16(al, bh[nf], acc[nf], 0, 0, 0);
            acc[nf] = __builtin_amdgcn_mfma_f32_16x16x32_f16(ah, bl8[nf], acc[nf], 0, 0, 0);
            acc[nf] = __builtin_amdgcn_mfma_f32_16x16x32_f16(ah, bh[nf], acc[nf], 0, 0, 0);
          }
        }
        __syncthreads();
      }

#pragma unroll
      for (int nf = 0; nf < 8; ++nf) {
        int code = nt * 128 + nf * 16 + l15;
#pragma unroll
        for (int r = 0; r < 4; ++r) {
          float s = fmaf(-2.f, acc[nf][r], cnv[nf]);
          m2[r] = fminf(m2[r], fmaxf(m1[r], s));
          bool lt = s < m1[r];
          i1[r] = lt ? code : i1[r];
          m1[r] = lt ? s : m1[r];
        }
      }
    }

#pragma unroll
    for (int off = 1; off < 16; off <<= 1) {
#pragma unroll
      for (int r = 0; r < 4; ++r) {
        float o1 = __shfl_xor(m1[r], off);
        int   oi = __shfl_xor(i1[r], off);
        float o2 = __shfl_xor(m2[r], off);
        bool bb = (o1 < m1[r]) || (o1 == m1[r] && oi < i1[r]);
        float hi = fmaxf(m1[r], o1);
        m2[r] = fminf(hi, fminf(m2[r], o2));
        m1[r] = bb ? o1 : m1[r];
        i1[r] = bb ? oi : i1[r];
      }
    }

    if (l15 == 0) {
#pragma unroll
      for (int r = 0; r < 4; ++r) {
        int fr = w * 16 + lhi * 4 + r;
        int pos = base + fr;
        if (pos < n) {
          pm1[cq * NRMAX + pos] = m1[r];
          pm2[cq * NRMAX + pos] = m2[r];
          pi1[cq * NRMAX + pos] = i1[r];
        }
      }
    }
  }
}

// ---------------- merge: combine 4 code-quarter partials per flagged row ----------------
__global__ __launch_bounds__(256) void vq_merge(
    const int* __restrict__ list, const int* __restrict__ cnt,
    const float* __restrict__ pm1, const float* __restrict__ pm2,
    const int* __restrict__ pi1, int* __restrict__ idx_arr,
    int* __restrict__ list2, int* __restrict__ cnt2) {
  int i = blockIdx.x * 256 + threadIdx.x;
  int n = *cnt;
  if (i >= n) return;
  float m1 = pm1[i], m2 = pm2[i];
  int   i1 = pi1[i];
#pragma unroll
  for (int cq = 1; cq < 4; ++cq) {
    float o1 = pm1[cq * NRMAX + i];
    float o2 = pm2[cq * NRMAX + i];
    int   oi = pi1[cq * NRMAX + i];
    bool bb = (o1 < m1) || (o1 == m1 && oi < i1);
    float hi = fmaxf(m1, o1);
    m2 = fminf(hi, fminf(m2, o2));
    m1 = bb ? o1 : m1;
    i1 = bb ? oi : i1;
  }
  int row = list[i];
  idx_arr[row] = i1;
  if (m2 - m1 < DELTA2) {
    int p = atomicAdd(cnt2, 1);
    list2[p] = row;
  }
}

// ---------------- rescue: exact fp32 recompute (round-1-identical chain) ----------------
__global__ __launch_bounds__(256) void vq_rescue(
    const float* __restrict__ z, const float* __restrict__ cb,
    const float* __restrict__ cnw, const int* __restrict__ list,
    const int* __restrict__ cnt, int* __restrict__ idx_arr) {
  __shared__ float zs[256];
  __shared__ float As;
  __shared__ float wmin[4];
  __shared__ int   widx[4];

  const int t = threadIdx.x;
  const int l = t & 63, w = t >> 6;
  const int n = *cnt;

  for (int i = blockIdx.x; i < n; i += gridDim.x) {
    int row = list[i];
    __syncthreads();
    if (t < 64) ((float4*)zs)[t] = ((const float4*)(z + (size_t)row * DIM))[t];
    __syncthreads();
    if (t < 4) {
      double s = 0.0;
      const float* zz = zs + t * 64;
      for (int d = 0; d < 64; ++d) { float v = zz[d]; s += (double)v * v; }
      s += __shfl_xor(s, 1);
      s += __shfl_xor(s, 2);
      if (t == 0) As = (float)s;
    }
    __syncthreads();
    float Af = As;

    const float4* c0 = (const float4*)(cb + (size_t)(t      ) * DIM);
    const float4* c1 = (const float4*)(cb + (size_t)(t + 256) * DIM);
    const float4* c2 = (const float4*)(cb + (size_t)(t + 512) * DIM);
    const float4* c3 = (const float4*)(cb + (size_t)(t + 768) * DIM);
    float a0 = 0.f, a1 = 0.f, a2 = 0.f, a3 = 0.f;
    for (int d4 = 0; d4 < 64; ++d4) {
      float4 zq = *(const float4*)(zs + d4 * 4);
      float4 va = c0[d4], vb = c1[d4], vc = c2[d4], vd = c3[d4];
      a0 = fmaf(zq.x, va.x, a0); a0 = fmaf(zq.y, va.y, a0);
      a0 = fmaf(zq.z, va.z, a0); a0 = fmaf(zq.w, va.w, a0);
      a1 = fmaf(zq.x, vb.x, a1); a1 = fmaf(zq.y, vb.y, a1);
      a1 = fmaf(zq.z, vb.z, a1); a1 = fmaf(zq.w, vb.w, a1);
      a2 = fmaf(zq.x, vc.x, a2); a2 = fmaf(zq.y, vc.y, a2);
      a2 = fmaf(zq.z, vc.z, a2); a2 = fmaf(zq.w, vc.w, a2);
      a3 = fmaf(zq.x, vd.x, a3); a3 = fmaf(zq.y, vd.y, a3);
      a3 = fmaf(zq.z, vd.z, a3); a3 = fmaf(zq.w, vd.w, a3);
    }
    float accs[4] = {a0, a1, a2, a3};
    float mv = 3.0e38f; int mi = 0;
#pragma unroll
    for (int j = 0; j < 4; ++j) {
      int code = t + j * 256;
      float t1 = fmaf(-2.f, accs[j], Af);
      float t2 = t1 + cnw[code];
      if (t2 < mv) { mv = t2; mi = code; }
    }
#pragma unroll
    for (int off = 1; off < 64; off <<= 1) {
      float ov = __shfl_xor(mv, off);
      int   oi = __shfl_xor(mi, off);
      if (ov < mv || (ov == mv && oi < mi)) { mv = ov; mi = oi; }
    }
    if (l == 0) { wmin[w] = mv; widx[w] = mi; }
    __syncthreads();
    if (t == 0) {
      float bm = wmin[0]; int bi = widx[0];
#pragma unroll
      for (int q = 1; q < 4; ++q)
        if (wmin[q] < bm || (wmin[q] == bm && widx[q] < bi)) { bm = wmin[q]; bi = widx[q]; }
      idx_arr[row] = bi;
    }
    __syncthreads();
  }
}

// ---------------- epilogue: gather, straight-through write, per-block loss ----------------
__global__ __launch_bounds__(256) void vq_epilogue(
    const float* __restrict__ z, const float* __restrict__ cb,
    const int* __restrict__ idx_arr, float* __restrict__ out_q,
    float* __restrict__ out_idx, double* __restrict__ partial) {
  __shared__ int idxs[16];
  __shared__ double lw[4];
  const int t = threadIdx.x;
  const int b0 = blockIdx.x * 16;
  if (t < 16) {
    int k = idx_arr[b0 + t];
    idxs[t] = k;
    out_idx[b0 + t] = (float)k;
  }
  __syncthreads();
  const float4* zb = (const float4*)(z + (size_t)b0 * DIM);
  float4* qb = (float4*)(out_q + (size_t)b0 * DIM);
  double ls = 0.0;
#pragma unroll
  for (int p = 0; p < 4; ++p) {
    int fi = p * 256 + t;
    int ki = idxs[fi >> 6];
    float4 zv = zb[fi];
    float4 cv = ((const float4*)(cb + (size_t)ki * DIM))[fi & 63];
    float dx = cv.x - zv.x, dy = cv.y - zv.y, dz = cv.z - zv.z, dw = cv.w - zv.w;
    float4 o; o.x = zv.x + dx; o.y = zv.y + dy; o.z = zv.z + dz; o.w = zv.w + dw;
    qb[fi] = o;
    ls += (double)dx * dx + (double)dy * dy + (double)dz * dz + (double)dw * dw;
  }
#pragma unroll
  for (int off = 1; off < 64; off <<= 1) ls += __shfl_xor(ls, off);
  if ((t & 63) == 0) lw[t >> 6] = ls;
  __syncthreads();
  if (t == 0) partial[blockIdx.x] = lw[0] + lw[1] + lw[2] + lw[3];
}

// ---------------- finalize losses ----------------
__global__ __launch_bounds__(256) void finalize_kernel(const double* __restrict__ partial,
                                                       float* __restrict__ out_losses) {
  __shared__ double lw[4];
  const int t = threadIdx.x;
  double s = 0.0;
  for (int i = t; i < 4096; i += 256) s += partial[i];
#pragma unroll
  for (int off = 1; off < 64; off <<= 1) s += __shfl_xor(s, off);
  if ((t & 63) == 0) lw[t >> 6] = s;
  __syncthreads();
  if (t == 0) {
    double mse = (lw[0] + lw[1] + lw[2] + lw[3]) / ((double)NROWS * (double)DIM);
    out_losses[0] = (float)(0.25 * mse);  // commitment
    out_losses[1] = (float)mse;           // embedding
  }
}

extern "C" void kernel_launch(void* const* d_in, const int* in_sizes, int n_in,
                              void* d_out, int out_size, void* d_ws, size_t ws_size,
                              hipStream_t stream) {
  const float* z  = (const float*)d_in[0];
  const float* cb = (const float*)d_in[1];
  float* out = (float*)d_out;

  char* ws = (char*)d_ws;
  int*            cnt     = (int*)(ws + 0);
  int*            cnt2    = (int*)(ws + 8);
  float*          cnorm   = (float*)(ws + 4096);
  double*         partial = (double*)(ws + 8192);                 // 4096 doubles -> 40960
  int*            idx_arr = (int*)(ws + 40960);                   // 256KB -> 303104
  int*            list    = (int*)(ws + 303104);                  // 256KB -> 565248
  int*            list2   = (int*)(ws + 565248);                  // 256KB -> 827392
  unsigned short* cbh     = (unsigned short*)(ws + 827392);       // 512KB -> 1351680
  unsigned short* cbl     = (unsigned short*)(ws + 1351680);      // 512KB -> 1875968
  float*          pm1     = (float*)(ws + 1875968);               // 1MB  -> 2924544
  float*          pm2     = (float*)(ws + 2924544);               // 1MB  -> 3973120
  int*            pi1     = (int*)(ws + 3973120);                 // 1MB  -> 5021696

  float* out_q      = out;             // 16777216
  float* out_losses = out + 16777216;  // 2
  float* out_idx    = out + 16777218;  // 65536

  prep_kernel<<<16, 256, 0, stream>>>(cb, cnorm, cbh, cbl, cnt, cnt2);
  vq_mfma<<<NROWS / 128, 256, 0, stream>>>(z, cbh, cnorm, idx_arr, list, cnt);
  vq_refine<<<1024, 256, 0, stream>>>(z, cbh, cbl, cnorm, list, cnt, pm1, pm2, pi1);
  vq_merge<<<NRMAX / 256, 256, 0, stream>>>(list, cnt, pm1, pm2, pi1, idx_arr, list2, cnt2);
  vq_rescue<<<256, 256, 0, stream>>>(z, cb, cnorm, list2, cnt2, idx_arr);
  vq_epilogue<<<NROWS / 16, 256, 0, stream>>>(z, cb, idx_arr, out_q, out_idx, partial);
  finalize_kernel<<<1, 256, 0, stream>>>(partial, out_losses);
}